// Round 7
// baseline (1014.541 us; speedup 1.0000x reference)
//
#include <hip/hip_runtime.h>
#include <hip/hip_fp16.h>
#include <math.h>

#define HID 16
#define RANGES 8

// ---------------------------------------------------------------------------
// CSR build: count in-degrees, hierarchical prefix-sum, range-filtered scatter
// ---------------------------------------------------------------------------

__global__ void count_deg(const int* __restrict__ dst, int* __restrict__ cnt, int E) {
    int e = blockIdx.x * blockDim.x + threadIdx.x;
    if (e < E) atomicAdd(&cnt[__builtin_nontemporal_load(dst + e)], 1);
}

__global__ void block_reduce(const int* __restrict__ cnt, int* __restrict__ bsum, int N) {
    int i = blockIdx.x * blockDim.x + threadIdx.x;
    int v = (i < N) ? cnt[i] : 0;
#pragma unroll
    for (int o = 1; o < 64; o <<= 1) v += __shfl_xor(v, o);
    __shared__ int ws[4];
    int lane = threadIdx.x & 63;
    int wid = threadIdx.x >> 6;
    if (lane == 0) ws[wid] = v;
    __syncthreads();
    if (threadIdx.x == 0) bsum[blockIdx.x] = ws[0] + ws[1] + ws[2] + ws[3];
}

__global__ void scan_bsums(int* __restrict__ bsum, int* __restrict__ row_ptr,
                           int nb, int N) {
    __shared__ int s[1024];
    int t = threadIdx.x;
    int v = (t < nb) ? bsum[t] : 0;
    s[t] = v;
    __syncthreads();
    for (int o = 1; o < 1024; o <<= 1) {
        int add = (t >= o) ? s[t - o] : 0;
        __syncthreads();
        s[t] += add;
        __syncthreads();
    }
    if (t < nb) bsum[t] = s[t] - v;            // exclusive
    if (t == 0) row_ptr[N] = s[1023];          // total == E
}

// w9 = 0.9/deg (alpha folded); dinv = deg^-1/2
__global__ void finalize(const int* __restrict__ cnt, const int* __restrict__ bsum,
                         int* __restrict__ row_ptr, int* __restrict__ cursor,
                         float* __restrict__ w9, float* __restrict__ dinv, int N) {
    __shared__ int s[256];
    int t = threadIdx.x;
    int i = blockIdx.x * blockDim.x + t;
    int c = (i < N) ? cnt[i] : 0;
    s[t] = c;
    __syncthreads();
    for (int o = 1; o < 256; o <<= 1) {
        int add = (t >= o) ? s[t - o] : 0;
        __syncthreads();
        s[t] += add;
        __syncthreads();
    }
    if (i < N) {
        int off = bsum[blockIdx.x] + s[t] - c;
        row_ptr[i] = off;
        cursor[i]  = off;
        float deg = (float)(c + 1);             // +1 self-loop
        w9[i]   = 0.9f / deg;
        dinv[i] = rsqrtf(deg);
    }
}

// Range-filtered scatter, 4-edge unroll: four independent atomic->write chains
// per iteration (fill_csr measured 46 G req/s vs ~75 G machine ceiling; the
// serial atomic+store chain was the limiter, not traffic).
__global__ void fill_csr(const int* __restrict__ src, const int* __restrict__ dst,
                         int* __restrict__ cursor, int* __restrict__ col,
                         int E, int range_step, int N) {
    int r = blockIdx.x & (RANGES - 1);
    int chunk = blockIdx.x >> 3;
    int nchunks = gridDim.x >> 3;
    int lo = r * range_step;
    int hi = min(lo + range_step, N);
    int stride = nchunks * blockDim.x;
    int e0 = chunk * blockDim.x + threadIdx.x;
    for (int e = e0; e < E; e += 4 * stride) {
        int ea = e, eb = e + stride, ec = e + 2 * stride, ed = e + 3 * stride;
        int d0 = __builtin_nontemporal_load(dst + ea);
        int d1 = (eb < E) ? __builtin_nontemporal_load(dst + eb) : -1;
        int d2 = (ec < E) ? __builtin_nontemporal_load(dst + ec) : -1;
        int d3 = (ed < E) ? __builtin_nontemporal_load(dst + ed) : -1;
        bool m0 = (d0 >= lo) && (d0 < hi);
        bool m1 = (d1 >= lo) && (d1 < hi);
        bool m2 = (d2 >= lo) && (d2 < hi);
        bool m3 = (d3 >= lo) && (d3 < hi);
        int s0 = m0 ? __builtin_nontemporal_load(src + ea) : 0;
        int s1 = m1 ? __builtin_nontemporal_load(src + eb) : 0;
        int s2 = m2 ? __builtin_nontemporal_load(src + ec) : 0;
        int s3 = m3 ? __builtin_nontemporal_load(src + ed) : 0;
        int p0 = m0 ? atomicAdd(&cursor[d0], 1) : 0;
        int p1 = m1 ? atomicAdd(&cursor[d1], 1) : 0;
        int p2 = m2 ? atomicAdd(&cursor[d2], 1) : 0;
        int p3 = m3 ? atomicAdd(&cursor[d3], 1) : 0;
        if (m0) col[p0] = s0;
        if (m1) col[p1] = s1;
        if (m2) col[p2] = s2;
        if (m3) col[p3] = s3;
    }
}

// ---------------------------------------------------------------------------
// MLP encoder: h0 = relu(relu(x*W1+b1) @ W2 + b2)
// g0f = dinv*h0 (fp32 alpha term); gh0 = fp16 copy (round-1 gather source)
// ---------------------------------------------------------------------------
__global__ void encoder(const float* __restrict__ x, const float* __restrict__ W1,
                        const float* __restrict__ b1, const float* __restrict__ W2,
                        const float* __restrict__ b2, const float* __restrict__ dinv,
                        float* __restrict__ g0f, __half* __restrict__ gh0, int N) {
    int v = blockIdx.x * blockDim.x + threadIdx.x;
    if (v >= N) return;
    float xv = x[v];
    float h1[HID];
#pragma unroll
    for (int j = 0; j < HID; ++j) h1[j] = fmaxf(xv * W1[j] + b1[j], 0.0f);
    float dv = dinv[v];
#pragma unroll
    for (int j = 0; j < HID; ++j) {
        float s = b2[j];
#pragma unroll
        for (int i = 0; i < HID; ++i) s += h1[i] * W2[i * HID + j];
        float g = dv * fmaxf(s, 0.0f);
        g0f[v * HID + j] = g;
        gh0[v * HID + j] = __float2half(g);
    }
}

// ---------------------------------------------------------------------------
// One APPNP round: g_out[v] = w9[v]*(sum_in g_in[src] + g_in[v]) + 0.1*g0[v]
// g state fp16 (3.2MB, L2-resident); accumulate fp32. 16 lanes/node; group
// vector-loads 16 col entries, shfl-broadcasts each src id -> 16 independent
// gathers in flight per subgroup.
// ---------------------------------------------------------------------------
__global__ void prop(const __half* __restrict__ gin, const float* __restrict__ g0f,
                     const int* __restrict__ row_ptr, const int* __restrict__ col,
                     const float* __restrict__ w9, __half* __restrict__ gout, int N) {
    int gid = blockIdx.x * blockDim.x + threadIdx.x;
    int v = gid >> 4;
    if (v >= N) return;
    int j = threadIdx.x & 15;

    int s = row_ptr[v];
    int e = row_ptr[v + 1];

    float acc = __half2float(gin[v * HID + j]);   // self-loop term

    int k = s;
    for (; k + 16 <= e; k += 16) {
        int cv = __builtin_nontemporal_load(col + k + j);
#pragma unroll
        for (int i = 0; i < 16; ++i) {
            int c = __shfl(cv, i, 16);
            acc += __half2float(gin[c * HID + j]);
        }
    }
    int rem = e - k;
    int cvt = (j < rem) ? __builtin_nontemporal_load(col + k + j) : 0;
    for (int i = 0; i < rem; ++i) {
        int c = __shfl(cvt, i, 16);
        acc += __half2float(gin[c * HID + j]);
    }

    gout[v * HID + j] = __float2half(w9[v] * acc + 0.1f * g0f[v * HID + j]);
}

// Final round fused with the head: compute g_final in registers, reduce
// g_final . W3 across the 16-lane group, write y directly (no gout write).
__global__ void prop_last(const __half* __restrict__ gin, const float* __restrict__ g0f,
                          const int* __restrict__ row_ptr, const int* __restrict__ col,
                          const float* __restrict__ w9, const float* __restrict__ dinv,
                          const float* __restrict__ W3, const float* __restrict__ b3,
                          float* __restrict__ y, int N) {
    int gid = blockIdx.x * blockDim.x + threadIdx.x;
    int v = gid >> 4;
    if (v >= N) return;
    int j = threadIdx.x & 15;

    int s = row_ptr[v];
    int e = row_ptr[v + 1];

    float acc = __half2float(gin[v * HID + j]);

    int k = s;
    for (; k + 16 <= e; k += 16) {
        int cv = __builtin_nontemporal_load(col + k + j);
#pragma unroll
        for (int i = 0; i < 16; ++i) {
            int c = __shfl(cv, i, 16);
            acc += __half2float(gin[c * HID + j]);
        }
    }
    int rem = e - k;
    int cvt = (j < rem) ? __builtin_nontemporal_load(col + k + j) : 0;
    for (int i = 0; i < rem; ++i) {
        int c = __shfl(cvt, i, 16);
        acc += __half2float(gin[c * HID + j]);
    }

    float gfin = w9[v] * acc + 0.1f * g0f[v * HID + j];
    float t = gfin * W3[j];
    t += __shfl_xor(t, 1, 16);
    t += __shfl_xor(t, 2, 16);
    t += __shfl_xor(t, 4, 16);
    t += __shfl_xor(t, 8, 16);
    if (j == 0) y[v] = t / dinv[v] + b3[0];
}

extern "C" void kernel_launch(void* const* d_in, const int* in_sizes, int n_in,
                              void* d_out, int out_size, void* d_ws, size_t ws_size,
                              hipStream_t stream) {
    const float* x  = (const float*)d_in[0];
    const int* edge = (const int*)d_in[1];
    const float* W1 = (const float*)d_in[2];
    const float* b1 = (const float*)d_in[3];
    const float* W2 = (const float*)d_in[4];
    const float* b2 = (const float*)d_in[5];
    const float* W3 = (const float*)d_in[6];
    const float* b3 = (const float*)d_in[7];
    float* y = (float*)d_out;

    const int N = in_sizes[0];       // 100000
    const int E = in_sizes[1] / 2;   // 5000000
    const int* src = edge;
    const int* dst = edge + E;

    char* ws = (char*)d_ws;
    size_t off = 0;
    auto alloc = [&](size_t bytes) -> void* {
        void* p = ws + off;
        off += (bytes + 255) & ~(size_t)255;
        return p;
    };

    int*    cnt     = (int*)   alloc((size_t)N * 4);
    int*    row_ptr = (int*)   alloc((size_t)(N + 1) * 4);
    int*    cursor  = (int*)   alloc((size_t)N * 4);
    int*    col     = (int*)   alloc((size_t)E * 4);
    float*  w9      = (float*) alloc((size_t)N * 4);
    float*  dinv    = (float*) alloc((size_t)N * 4);
    float*  g0f     = (float*) alloc((size_t)N * HID * 4);
    __half* gA      = (__half*)alloc((size_t)N * HID * 2);
    __half* gB      = (__half*)alloc((size_t)N * HID * 2);
    int*    bsum    = (int*)   alloc(1024 * 4);

    const int nb = (N + 255) / 256;   // 391 <= 1024

    hipMemsetAsync(cnt, 0, (size_t)N * 4, stream);

    count_deg<<<(E + 255) / 256, 256, 0, stream>>>(dst, cnt, E);
    block_reduce<<<nb, 256, 0, stream>>>(cnt, bsum, N);
    scan_bsums<<<1, 1024, 0, stream>>>(bsum, row_ptr, nb, N);
    finalize<<<nb, 256, 0, stream>>>(cnt, bsum, row_ptr, cursor, w9, dinv, N);

    int range_step = (N + RANGES - 1) / RANGES;
    fill_csr<<<2048, 256, 0, stream>>>(src, dst, cursor, col, E, range_step, N);

    encoder<<<(N + 255) / 256, 256, 0, stream>>>(x, W1, b1, W2, b2, dinv, g0f, gA, N);

    const __half* gin = gA;
    __half* gout = gB;
    long long total = (long long)N * 16;       // 16 lanes per node
    int pgrid = (int)((total + 255) / 256);
    for (int k = 0; k < 9; ++k) {
        prop<<<pgrid, 256, 0, stream>>>(gin, g0f, row_ptr, col, w9, gout, N);
        const __half* t = gin; gin = gout; gout = (__half*)t;
    }
    prop_last<<<pgrid, 256, 0, stream>>>(gin, g0f, row_ptr, col, w9, dinv, W3, b3, y, N);
}

// Round 8
// 997.822 us; speedup vs baseline: 1.0168x; 1.0168x over previous
//
#include <hip/hip_runtime.h>
#include <hip/hip_fp16.h>
#include <math.h>

#define HID 16
#define RANGES 8

// ---------------------------------------------------------------------------
// CSR build: count in-degrees, hierarchical prefix-sum, range-filtered scatter
// ---------------------------------------------------------------------------

// Plain (cached) loads: this pass warms L3 with dst for fill_csr's 8 re-reads.
__global__ void count_deg(const int* __restrict__ dst, int* __restrict__ cnt, int E) {
    int e = blockIdx.x * blockDim.x + threadIdx.x;
    if (e < E) atomicAdd(&cnt[dst[e]], 1);
}

__global__ void block_reduce(const int* __restrict__ cnt, int* __restrict__ bsum, int N) {
    int i = blockIdx.x * blockDim.x + threadIdx.x;
    int v = (i < N) ? cnt[i] : 0;
#pragma unroll
    for (int o = 1; o < 64; o <<= 1) v += __shfl_xor(v, o);
    __shared__ int ws[4];
    int lane = threadIdx.x & 63;
    int wid = threadIdx.x >> 6;
    if (lane == 0) ws[wid] = v;
    __syncthreads();
    if (threadIdx.x == 0) bsum[blockIdx.x] = ws[0] + ws[1] + ws[2] + ws[3];
}

__global__ void scan_bsums(int* __restrict__ bsum, int* __restrict__ row_ptr,
                           int nb, int N) {
    __shared__ int s[1024];
    int t = threadIdx.x;
    int v = (t < nb) ? bsum[t] : 0;
    s[t] = v;
    __syncthreads();
    for (int o = 1; o < 1024; o <<= 1) {
        int add = (t >= o) ? s[t - o] : 0;
        __syncthreads();
        s[t] += add;
        __syncthreads();
    }
    if (t < nb) bsum[t] = s[t] - v;            // exclusive
    if (t == 0) row_ptr[N] = s[1023];          // total == E
}

// Stage 3 + encoder fused: scan cnt -> row_ptr/cursor/w9, compute dinv, and
// immediately run the per-node MLP encoder (dinv is in-register here).
__global__ void finalize_encode(const int* __restrict__ cnt, const int* __restrict__ bsum,
                                int* __restrict__ row_ptr, int* __restrict__ cursor,
                                float* __restrict__ w9, float* __restrict__ dinv,
                                const float* __restrict__ x, const float* __restrict__ W1,
                                const float* __restrict__ b1, const float* __restrict__ W2,
                                const float* __restrict__ b2,
                                float* __restrict__ g0f, __half* __restrict__ gh0, int N) {
    __shared__ int s[256];
    int t = threadIdx.x;
    int i = blockIdx.x * blockDim.x + t;
    int c = (i < N) ? cnt[i] : 0;
    s[t] = c;
    __syncthreads();
    for (int o = 1; o < 256; o <<= 1) {
        int add = (t >= o) ? s[t - o] : 0;
        __syncthreads();
        s[t] += add;
        __syncthreads();
    }
    if (i >= N) return;
    int off = bsum[blockIdx.x] + s[t] - c;
    row_ptr[i] = off;
    cursor[i]  = off;
    float deg = (float)(c + 1);                 // +1 self-loop
    w9[i]   = 0.9f / deg;
    float dv = rsqrtf(deg);
    dinv[i] = dv;

    // ---- encoder: g0 = dinv * relu(relu(x*W1+b1)@W2+b2) ----
    float xv = x[i];
    float h1[HID];
#pragma unroll
    for (int j = 0; j < HID; ++j) h1[j] = fmaxf(xv * W1[j] + b1[j], 0.0f);
#pragma unroll
    for (int j = 0; j < HID; ++j) {
        float acc = b2[j];
#pragma unroll
        for (int q = 0; q < HID; ++q) acc += h1[q] * W2[q * HID + j];
        float g = dv * fmaxf(acc, 0.0f);
        g0f[i * HID + j] = g;
        gh0[i * HID + j] = __float2half(g);
    }
}

// Range-filtered scatter: blockIdx%8 selects a dst range; round-robin
// workgroup->XCD dispatch keeps each col window mostly in one XCD's L2.
// Cached (non-NT) loads: dst/src stay L3-resident across the 8 passes.
__global__ void fill_csr(const int* __restrict__ src, const int* __restrict__ dst,
                         int* __restrict__ cursor, int* __restrict__ col,
                         int E, int range_step, int N) {
    int r = blockIdx.x & (RANGES - 1);
    int chunk = blockIdx.x >> 3;
    int nchunks = gridDim.x >> 3;
    int lo = r * range_step;
    int hi = min(lo + range_step, N);
    int stride = nchunks * blockDim.x;
    for (int e = chunk * blockDim.x + threadIdx.x; e < E; e += stride) {
        int d = dst[e];
        if (d >= lo && d < hi) {
            int sv = src[e];
            int p = atomicAdd(&cursor[d], 1);
            col[p] = sv;
        }
    }
}

// ---------------------------------------------------------------------------
// One APPNP round: g_out[v] = w9[v]*(sum_in g_in[src] + g_in[v]) + 0.1*g0[v]
// g state fp16 (3.2MB, L2-resident); accumulate fp32. 16 lanes/node; group
// vector-loads 16 col entries, shfl-broadcasts each src id -> 16 independent
// gathers in flight per subgroup.
// ---------------------------------------------------------------------------
__global__ void prop(const __half* __restrict__ gin, const float* __restrict__ g0f,
                     const int* __restrict__ row_ptr, const int* __restrict__ col,
                     const float* __restrict__ w9, __half* __restrict__ gout, int N) {
    int gid = blockIdx.x * blockDim.x + threadIdx.x;
    int v = gid >> 4;
    if (v >= N) return;
    int j = threadIdx.x & 15;

    int s = row_ptr[v];
    int e = row_ptr[v + 1];

    float acc = __half2float(gin[v * HID + j]);   // self-loop term

    int k = s;
    for (; k + 16 <= e; k += 16) {
        int cv = __builtin_nontemporal_load(col + k + j);   // col is single-use stream
#pragma unroll
        for (int i = 0; i < 16; ++i) {
            int c = __shfl(cv, i, 16);
            acc += __half2float(gin[c * HID + j]);
        }
    }
    int rem = e - k;
    int cvt = (j < rem) ? __builtin_nontemporal_load(col + k + j) : 0;
    for (int i = 0; i < rem; ++i) {
        int c = __shfl(cvt, i, 16);
        acc += __half2float(gin[c * HID + j]);
    }

    gout[v * HID + j] = __float2half(w9[v] * acc + 0.1f * g0f[v * HID + j]);
}

// Final round fused with the head: compute g_final in registers, reduce
// g_final . W3 across the 16-lane group, write y directly (no gout write).
__global__ void prop_last(const __half* __restrict__ gin, const float* __restrict__ g0f,
                          const int* __restrict__ row_ptr, const int* __restrict__ col,
                          const float* __restrict__ w9, const float* __restrict__ dinv,
                          const float* __restrict__ W3, const float* __restrict__ b3,
                          float* __restrict__ y, int N) {
    int gid = blockIdx.x * blockDim.x + threadIdx.x;
    int v = gid >> 4;
    if (v >= N) return;
    int j = threadIdx.x & 15;

    int s = row_ptr[v];
    int e = row_ptr[v + 1];

    float acc = __half2float(gin[v * HID + j]);

    int k = s;
    for (; k + 16 <= e; k += 16) {
        int cv = __builtin_nontemporal_load(col + k + j);
#pragma unroll
        for (int i = 0; i < 16; ++i) {
            int c = __shfl(cv, i, 16);
            acc += __half2float(gin[c * HID + j]);
        }
    }
    int rem = e - k;
    int cvt = (j < rem) ? __builtin_nontemporal_load(col + k + j) : 0;
    for (int i = 0; i < rem; ++i) {
        int c = __shfl(cvt, i, 16);
        acc += __half2float(gin[c * HID + j]);
    }

    float gfin = w9[v] * acc + 0.1f * g0f[v * HID + j];
    float t = gfin * W3[j];
    t += __shfl_xor(t, 1, 16);
    t += __shfl_xor(t, 2, 16);
    t += __shfl_xor(t, 4, 16);
    t += __shfl_xor(t, 8, 16);
    if (j == 0) y[v] = t / dinv[v] + b3[0];
}

extern "C" void kernel_launch(void* const* d_in, const int* in_sizes, int n_in,
                              void* d_out, int out_size, void* d_ws, size_t ws_size,
                              hipStream_t stream) {
    const float* x  = (const float*)d_in[0];
    const int* edge = (const int*)d_in[1];
    const float* W1 = (const float*)d_in[2];
    const float* b1 = (const float*)d_in[3];
    const float* W2 = (const float*)d_in[4];
    const float* b2 = (const float*)d_in[5];
    const float* W3 = (const float*)d_in[6];
    const float* b3 = (const float*)d_in[7];
    float* y = (float*)d_out;

    const int N = in_sizes[0];       // 100000
    const int E = in_sizes[1] / 2;   // 5000000
    const int* src = edge;
    const int* dst = edge + E;

    char* ws = (char*)d_ws;
    size_t off = 0;
    auto alloc = [&](size_t bytes) -> void* {
        void* p = ws + off;
        off += (bytes + 255) & ~(size_t)255;
        return p;
    };

    int*    cnt     = (int*)   alloc((size_t)N * 4);
    int*    row_ptr = (int*)   alloc((size_t)(N + 1) * 4);
    int*    cursor  = (int*)   alloc((size_t)N * 4);
    int*    col     = (int*)   alloc((size_t)E * 4);
    float*  w9      = (float*) alloc((size_t)N * 4);
    float*  dinv    = (float*) alloc((size_t)N * 4);
    float*  g0f     = (float*) alloc((size_t)N * HID * 4);
    __half* gA      = (__half*)alloc((size_t)N * HID * 2);
    __half* gB      = (__half*)alloc((size_t)N * HID * 2);
    int*    bsum    = (int*)   alloc(1024 * 4);

    const int nb = (N + 255) / 256;   // 391 <= 1024

    hipMemsetAsync(cnt, 0, (size_t)N * 4, stream);

    count_deg<<<(E + 255) / 256, 256, 0, stream>>>(dst, cnt, E);
    block_reduce<<<nb, 256, 0, stream>>>(cnt, bsum, N);
    scan_bsums<<<1, 1024, 0, stream>>>(bsum, row_ptr, nb, N);
    finalize_encode<<<nb, 256, 0, stream>>>(cnt, bsum, row_ptr, cursor, w9, dinv,
                                            x, W1, b1, W2, b2, g0f, gA, N);

    int range_step = (N + RANGES - 1) / RANGES;
    fill_csr<<<2048, 256, 0, stream>>>(src, dst, cursor, col, E, range_step, N);

    const __half* gin = gA;
    __half* gout = gB;
    long long total = (long long)N * 16;       // 16 lanes per node
    int pgrid = (int)((total + 255) / 256);
    for (int k = 0; k < 9; ++k) {
        prop<<<pgrid, 256, 0, stream>>>(gin, g0f, row_ptr, col, w9, gout, N);
        const __half* t = gin; gin = gout; gout = (__half*)t;
    }
    prop_last<<<pgrid, 256, 0, stream>>>(gin, g0f, row_ptr, col, w9, dinv, W3, b3, y, N);
}